// Round 10
// baseline (218.813 us; speedup 1.0000x reference)
//
#include <hip/hip_runtime.h>
#include <hip/hip_bf16.h>

#define T_TOK 2048
#define H_DIM 1024
#define E_N   8
#define I_DIM 2048

#define NT_MAX 40         // sum ceil(cnt_e/128) <= 4096/128 + 7 = 39
#define MAX_SLOTS 5120    // 40 tiles * 128 rows

typedef unsigned short u16;
typedef unsigned int   u32;
typedef __bf16 bf16_t;
typedef bf16_t bf16x8 __attribute__((ext_vector_type(8)));
typedef u16    u16x8  __attribute__((ext_vector_type(8)));
typedef float  f32x4  __attribute__((ext_vector_type(4)));

#define MFMA __builtin_amdgcn_mfma_f32_16x16x32_bf16

__device__ __forceinline__ u16 bfbits(float f) {
    bf16_t b = (bf16_t)f;
    return __builtin_bit_cast(u16, b);
}

__device__ __forceinline__ void gload_lds16(const void* g, void* l) {
    __builtin_amdgcn_global_load_lds(
        (const __attribute__((address_space(1))) void*)g,
        (__attribute__((address_space(3))) void*)l, 16, 0, 0);
}

// B LDS tile: col n (0..127), k-slot kb (0..7)
__device__ __forceinline__ int tile_off(int n, int kb) {
    return n * 64 + ((kb ^ ((n >> 1) & 7)) << 3);
}
// A LDS tile (linear gload_lds dest, source k-group pre-XOR'd): row, kslot
__device__ __forceinline__ int a_off(int row, int kslot) {
    return row * 64 + ((kslot ^ (row & 7)) << 3);
}

// ---------------- router: 4 tokens/block
__global__ __launch_bounds__(256) void router_k(
    const float* __restrict__ x, const float* __restrict__ rw,
    int* __restrict__ cnt, int* __restrict__ tok, float* __restrict__ wts,
    u16* __restrict__ xbf)
{
    int wid = threadIdx.x >> 6, lane = threadIdx.x & 63;
    int t = blockIdx.x * 4 + wid;
    const float* xr = x + (size_t)t * H_DIM;
    u16* xbr = xbf + (size_t)t * H_DIM;

    float acc[E_N];
#pragma unroll
    for (int e = 0; e < E_N; e++) acc[e] = 0.f;
    for (int j = 0; j < H_DIM / 64; j++) {
        float xv = xr[lane + 64 * j];
        xbr[lane + 64 * j] = bfbits(xv);
#pragma unroll
        for (int e = 0; e < E_N; e++)
            acc[e] += xv * rw[e * H_DIM + lane + 64 * j];
    }
#pragma unroll
    for (int e = 0; e < E_N; e++) {
        float v = acc[e];
        for (int off = 32; off; off >>= 1) v += __shfl_xor(v, off);
        acc[e] = v;
    }
    if (lane == 0) {
        int i0 = 0; float m0 = acc[0];
#pragma unroll
        for (int e = 1; e < E_N; e++) if (acc[e] > m0) { m0 = acc[e]; i0 = e; }
        int i1 = -1; float m1 = -INFINITY;
#pragma unroll
        for (int e = 0; e < E_N; e++) if (e != i0 && acc[e] > m1) { m1 = acc[e]; i1 = e; }
        float w0 = 1.f / (1.f + expf(m1 - m0));
        float w1 = 1.f - w0;
        int p0 = atomicAdd(&cnt[i0], 1);
        tok[i0 * T_TOK + p0] = t; wts[i0 * T_TOK + p0] = w0;
        int p1 = atomicAdd(&cnt[i1], 1);
        tok[i1 * T_TOK + p1] = t; wts[i1 * T_TOK + p1] = w1;
    }
}

// ---------------- prefix + padded tile map (BM=128)
__global__ void prefix_k(const int* __restrict__ cnt, int* __restrict__ offs_pad,
                         int* __restrict__ tile_e, int* __restrict__ tile_row0,
                         int* __restrict__ ntiles)
{
    if (threadIdx.x == 0) {
        int s = 0, nt = 0;
        for (int e = 0; e < E_N; e++) {
            offs_pad[e] = s;
            int c = cnt[e];
            int t = (c + 127) >> 7;
            for (int i = 0; i < t; i++) { tile_e[nt] = e; tile_row0[nt] = i * 128; nt++; }
            s += t * 128;
        }
        offs_pad[E_N] = s;
        *ntiles = nt;
    }
}

// ---------------- gate/up grouped GEMM, fused fp32->bf16, counted-vmcnt pipeline
// tile 128x128, BK=64, 8 waves (4M x 2N). Even tiles -> LDS buf0/reg set0, odd -> buf1/set1.
// iter t: ASTAGE(t+1) ; MFMA(t) ; cvt+write set[(t+1)&1] ; load set[t&1] <- t+2 ;
//         s_waitcnt vmcnt(32) (A landed, 32 B-loads in flight) ; s_barrier.
__global__ __launch_bounds__(512, 2) void gateup_k(
    const u16* __restrict__ xbf, const float* __restrict__ wg, const float* __restrict__ wu,
    const int* __restrict__ cnt, const int* __restrict__ offs_pad,
    const int* __restrict__ tile_e, const int* __restrict__ tile_row0,
    const int* __restrict__ ntiles, const int* __restrict__ tok,
    u16* __restrict__ act)
{
    int q = gridDim.x >> 3;
    int phys = blockIdx.x;
    int logical = (phys & 7) * q + (phys >> 3);
    int tb = logical % NT_MAX;
    int p  = logical / NT_MAX;             // n-panel 0..15
    if (tb >= *ntiles) return;
    int e = tile_e[tb], row0 = tile_row0[tb];
    int cntE = cnt[e];
    int slot0 = offs_pad[e] + row0;
    int n0 = p * 128;

    __shared__ u16 AS[2][8192], GS[2][8192], US[2][8192];   // 96 KB -> 1 block/CU

    int tid = threadIdx.x;
    int lane = tid & 63, wid = tid >> 6;
    int wm = wid & 3, wn = wid >> 2;
    int l15 = lane & 15, lg = lane >> 4;

    // A staging sources (gathered token rows, k-group pre-XOR'd)
    const u16* asrc[2];
#pragma unroll
    for (int i = 0; i < 2; i++) {
        int row = (wid * 2 + i) * 8 + (lane >> 3);
        int rc = (row0 + row < cntE) ? (row0 + row) : (cntE - 1);
        asrc[i] = xbf + (size_t)tok[e * T_TOK + rc] * H_DIM + (((lane & 7) ^ (lane >> 3)) << 3);
    }
    int s0 = wid * 1024;

    // B staging: thread owns column bn, k-quarter kq (16 k's), both matrices
    int bn = tid & 127;
    int kq = tid >> 7;                     // 0..3
    const float* gsrc = wg + (size_t)e * H_DIM * I_DIM + n0 + bn;
    const float* usrc = wu + (size_t)e * H_DIM * I_DIM + n0 + bn;

    float g0[16], u0[16], g1[16], u1[16];

#define BLOAD(gs, us, t) { \
    _Pragma("unroll") \
    for (int j = 0; j < 16; j++) { \
        gs[j] = gsrc[(size_t)((t) * 64 + kq * 16 + j) * I_DIM]; \
        us[j] = usrc[(size_t)((t) * 64 + kq * 16 + j) * I_DIM]; } }

#define BWRITE(gs, us, nbuf) { \
    _Pragma("unroll") \
    for (int jb = 0; jb < 2; jb++) { \
        u16x8 pg, pu; \
        _Pragma("unroll") \
        for (int jj = 0; jj < 8; jj++) { pg[jj] = bfbits(gs[jb * 8 + jj]); pu[jj] = bfbits(us[jb * 8 + jj]); } \
        *reinterpret_cast<u16x8*>(&GS[nbuf][tile_off(bn, kq * 2 + jb)]) = pg; \
        *reinterpret_cast<u16x8*>(&US[nbuf][tile_off(bn, kq * 2 + jb)]) = pu; } }

#define ASTAGE(nbuf, t) { \
    gload_lds16(asrc[0] + (size_t)(t) * 64, &AS[nbuf][s0]); \
    gload_lds16(asrc[1] + (size_t)(t) * 64, &AS[nbuf][s0 + 512]); }

    f32x4 accg[2][4], accu[2][4];
#pragma unroll
    for (int a = 0; a < 2; a++)
#pragma unroll
        for (int b = 0; b < 4; b++) { accg[a][b] = (f32x4)0.f; accu[a][b] = (f32x4)0.f; }

#define CLUSTER(bufi) { \
    _Pragma("unroll") \
    for (int ks = 0; ks < 2; ks++) { \
        bf16x8 af[2]; \
        _Pragma("unroll") \
        for (int mf = 0; mf < 2; mf++) { \
            int row = wm * 32 + mf * 16 + l15; \
            af[mf] = *reinterpret_cast<const bf16x8*>(&AS[bufi][a_off(row, ks * 4 + lg)]); } \
        int kbr = ks * 4 + lg; \
        _Pragma("unroll") \
        for (int nf = 0; nf < 4; nf++) { \
            int c = wn * 64 + nf * 16 + l15; \
            int o = tile_off(c, kbr); \
            bf16x8 bg = *reinterpret_cast<const bf16x8*>(&GS[bufi][o]); \
            bf16x8 bu = *reinterpret_cast<const bf16x8*>(&US[bufi][o]); \
            _Pragma("unroll") \
            for (int mf = 0; mf < 2; mf++) { \
                accg[mf][nf] = MFMA(af[mf], bg, accg[mf][nf], 0, 0, 0); \
                accu[mf][nf] = MFMA(af[mf], bu, accu[mf][nf], 0, 0, 0); } } } }

    // prologue (pinned order, full drain once): tile0 -> LDS0, tile1 -> set1 regs
    ASTAGE(0, 0);
    __builtin_amdgcn_sched_barrier(0);
    BLOAD(g0, u0, 0);
    __builtin_amdgcn_sched_barrier(0);
    BLOAD(g1, u1, 1);
    __builtin_amdgcn_sched_barrier(0);
    BWRITE(g0, u0, 0);
    __builtin_amdgcn_sched_barrier(0);
    asm volatile("s_waitcnt vmcnt(0) lgkmcnt(0)" ::: "memory");   // A(0)+set0+set1 all landed
    __builtin_amdgcn_s_barrier();
    __builtin_amdgcn_sched_barrier(0);

    for (int t2 = 0; t2 < 16; t2 += 2) {
        // ---- even iter t = t2 (buf0): consume set1 -> buf1 (tile t2+1), load set0 <- t2+2
        if (t2 + 1 < 16) ASTAGE(1, t2 + 1);
        CLUSTER(0);
        __builtin_amdgcn_sched_barrier(0);
        if (t2 + 1 < 16) BWRITE(g1, u1, 1);
        __builtin_amdgcn_sched_barrier(0);
        if (t2 + 2 < 16) {
            BLOAD(g0, u0, t2 + 2);
            __builtin_amdgcn_sched_barrier(0);
            asm volatile("s_waitcnt vmcnt(32) lgkmcnt(0)" ::: "memory");
        } else {
            asm volatile("s_waitcnt vmcnt(0) lgkmcnt(0)" ::: "memory");
        }
        __builtin_amdgcn_s_barrier();
        __builtin_amdgcn_sched_barrier(0);

        // ---- odd iter t = t2+1 (buf1): consume set0 -> buf0 (tile t2+2), load set1 <- t2+3
        {
            int t = t2 + 1;
            if (t + 1 < 16) ASTAGE(0, t + 1);
            CLUSTER(1);
            __builtin_amdgcn_sched_barrier(0);
            if (t + 1 < 16) {
                BWRITE(g0, u0, 0);
                __builtin_amdgcn_sched_barrier(0);
                if (t + 2 < 16) {
                    BLOAD(g1, u1, t + 2);
                    __builtin_amdgcn_sched_barrier(0);
                    asm volatile("s_waitcnt vmcnt(32) lgkmcnt(0)" ::: "memory");
                } else {
                    asm volatile("s_waitcnt vmcnt(0) lgkmcnt(0)" ::: "memory");
                }
                __builtin_amdgcn_s_barrier();
                __builtin_amdgcn_sched_barrier(0);
            }
            // t == 15: fall through to epilogue; nothing outstanding we still need
        }
    }
#undef BLOAD
#undef BWRITE
#undef ASTAGE
#undef CLUSTER

    // epilogue: silu(g)*u -> bf16; padded rows -> 0 (down_k reads them)
#pragma unroll
    for (int mf = 0; mf < 2; mf++)
#pragma unroll
        for (int j = 0; j < 4; j++) {
            int rl = wm * 32 + mf * 16 + lg * 4 + j;
            bool valid = (row0 + rl) < cntE;
            size_t base = (size_t)(slot0 + rl) * I_DIM + n0;
#pragma unroll
            for (int nf = 0; nf < 4; nf++) {
                float g = accg[mf][nf][j];
                float u = accu[mf][nf][j];
                float a = valid ? (g / (1.f + expf(-g))) * u : 0.f;
                act[base + wn * 64 + nf * 16 + l15] = bfbits(a);
            }
        }
}

// ---------------- down grouped GEMM, fused conversion, same pipeline, K split 2
__global__ __launch_bounds__(512, 4) void down_k(
    const u16* __restrict__ act, const float* __restrict__ wd,
    const int* __restrict__ cnt, const int* __restrict__ offs_pad,
    const int* __restrict__ tile_e, const int* __restrict__ tile_row0,
    const int* __restrict__ ntiles, const int* __restrict__ tok,
    const float* __restrict__ wts, float* __restrict__ out)
{
    int q = gridDim.x >> 3;
    int phys = blockIdx.x;
    int logical = (phys & 7) * q + (phys >> 3);
    int tb = logical % NT_MAX;
    int rest = logical / NT_MAX;
    int p  = rest & 7;
    int kh = rest >> 3;
    if (tb >= *ntiles) return;
    int e = tile_e[tb], row0 = tile_row0[tb];
    int cntE = cnt[e];
    int slot0 = offs_pad[e] + row0;
    int h0 = p * 128;

    __shared__ u16 AS[2][8192], DS[2][8192];    // 64 KB -> 2 blocks/CU

    int tid = threadIdx.x;
    int lane = tid & 63, wid = tid >> 6;
    int wm = wid & 3, wn = wid >> 2;
    int l15 = lane & 15, lg = lane >> 4;

    const u16* asrc[2];
#pragma unroll
    for (int i = 0; i < 2; i++) {
        int row = (wid * 2 + i) * 8 + (lane >> 3);
        asrc[i] = act + (size_t)(slot0 + row) * I_DIM + kh * 1024
                  + (((lane & 7) ^ (lane >> 3)) << 3);
    }
    int s0 = wid * 1024;

    int bn = tid & 127;
    int kq = tid >> 7;                     // 0..3, 16 k's each
    const float* dsrc = wd + ((size_t)e * I_DIM + kh * 1024) * H_DIM + h0 + bn;

    float v0[16], v1[16];

#define BLOAD(vs, t) { \
    _Pragma("unroll") \
    for (int j = 0; j < 16; j++) \
        vs[j] = dsrc[(size_t)((t) * 64 + kq * 16 + j) * H_DIM]; }

#define BWRITE(vs, nbuf) { \
    _Pragma("unroll") \
    for (int jb = 0; jb < 2; jb++) { \
        u16x8 pk; \
        _Pragma("unroll") \
        for (int jj = 0; jj < 8; jj++) pk[jj] = bfbits(vs[jb * 8 + jj]); \
        *reinterpret_cast<u16x8*>(&DS[nbuf][tile_off(bn, kq * 2 + jb)]) = pk; } }

#define ASTAGE(nbuf, t) { \
    gload_lds16(asrc[0] + (size_t)(t) * 64, &AS[nbuf][s0]); \
    gload_lds16(asrc[1] + (size_t)(t) * 64, &AS[nbuf][s0 + 512]); }

    f32x4 acc[2][4];
#pragma unroll
    for (int a = 0; a < 2; a++)
#pragma unroll
        for (int b = 0; b < 4; b++) acc[a][b] = (f32x4)0.f;

#define CLUSTER(bufi) { \
    _Pragma("unroll") \
    for (int ks = 0; ks < 2; ks++) { \
        bf16x8 af[2]; \
        _Pragma("unroll") \
        for (int mf = 0; mf < 2; mf++) { \
            int row = wm * 32 + mf * 16 + l15; \
            af[mf] = *reinterpret_cast<const bf16x8*>(&AS[bufi][a_off(row, ks * 4 + lg)]); } \
        int kbr = ks * 4 + lg; \
        _Pragma("unroll") \
        for (int nf = 0; nf < 4; nf++) { \
            int c = wn * 64 + nf * 16 + l15; \
            bf16x8 bd = *reinterpret_cast<const bf16x8*>(&DS[bufi][tile_off(c, kbr)]); \
            _Pragma("unroll") \
            for (int mf = 0; mf < 2; mf++) \
                acc[mf][nf] = MFMA(af[mf], bd, acc[mf][nf], 0, 0, 0); } } }

    // prologue (pinned order, full drain once)
    ASTAGE(0, 0);
    __builtin_amdgcn_sched_barrier(0);
    BLOAD(v0, 0);
    __builtin_amdgcn_sched_barrier(0);
    BLOAD(v1, 1);
    __builtin_amdgcn_sched_barrier(0);
    BWRITE(v0, 0);
    __builtin_amdgcn_sched_barrier(0);
    asm volatile("s_waitcnt vmcnt(0) lgkmcnt(0)" ::: "memory");
    __builtin_amdgcn_s_barrier();
    __builtin_amdgcn_sched_barrier(0);

    for (int t2 = 0; t2 < 16; t2 += 2) {
        if (t2 + 1 < 16) ASTAGE(1, t2 + 1);
        CLUSTER(0);
        __builtin_amdgcn_sched_barrier(0);
        if (t2 + 1 < 16) BWRITE(v1, 1);
        __builtin_amdgcn_sched_barrier(0);
        if (t2 + 2 < 16) {
            BLOAD(v0, t2 + 2);
            __builtin_amdgcn_sched_barrier(0);
            asm volatile("s_waitcnt vmcnt(16) lgkmcnt(0)" ::: "memory");
        } else {
            asm volatile("s_waitcnt vmcnt(0) lgkmcnt(0)" ::: "memory");
        }
        __builtin_amdgcn_s_barrier();
        __builtin_amdgcn_sched_barrier(0);

        {
            int t = t2 + 1;
            if (t + 1 < 16) ASTAGE(0, t + 1);
            CLUSTER(1);
            __builtin_amdgcn_sched_barrier(0);
            if (t + 1 < 16) {
                BWRITE(v0, 0);
                __builtin_amdgcn_sched_barrier(0);
                if (t + 2 < 16) {
                    BLOAD(v1, t + 2);
                    __builtin_amdgcn_sched_barrier(0);
                    asm volatile("s_waitcnt vmcnt(16) lgkmcnt(0)" ::: "memory");
                } else {
                    asm volatile("s_waitcnt vmcnt(0) lgkmcnt(0)" ::: "memory");
                }
                __builtin_amdgcn_s_barrier();
                __builtin_amdgcn_sched_barrier(0);
            }
        }
    }
#undef BLOAD
#undef BWRITE
#undef ASTAGE
#undef CLUSTER

#pragma unroll
    for (int mf = 0; mf < 2; mf++)
#pragma unroll
        for (int j = 0; j < 4; j++) {
            int rl = wm * 32 + mf * 16 + lg * 4 + j;
            int gr = row0 + rl;
            if (gr < cntE) {
                float w = wts[e * T_TOK + gr];
                int t   = tok[e * T_TOK + gr];
                size_t base = (size_t)t * H_DIM + h0;
#pragma unroll
                for (int nf = 0; nf < 4; nf++)
                    atomicAdd(&out[base + wn * 64 + nf * 16 + l15], acc[mf][nf][j] * w);
            }
        }
}

extern "C" void kernel_launch(void* const* d_in, const int* in_sizes, int n_in,
                              void* d_out, int out_size, void* d_ws, size_t ws_size,
                              hipStream_t stream)
{
    const float* x  = (const float*)d_in[0];
    const float* rw = (const float*)d_in[1];
    const float* wg = (const float*)d_in[2];
    const float* wu = (const float*)d_in[3];
    const float* wd = (const float*)d_in[4];
    float* out = (float*)d_out;

    char* ws = (char*)d_ws;
    int*   cnt       = (int*)(ws);
    int*   ntiles    = (int*)(ws + 32);
    int*   offs_pad  = (int*)(ws + 64);
    int*   tile_e    = (int*)(ws + 256);
    int*   tile_row0 = (int*)(ws + 512);
    int*   tok       = (int*)(ws + 64 * 1024);
    float* wts       = (float*)(ws + 128 * 1024);
    u16*   xbf       = (u16*)(ws + 256 * 1024);    // 4 MB
    u16*   act       = (u16*)(ws + 4608 * 1024);   // 20 MB

    size_t need = 4608ull * 1024 + (size_t)MAX_SLOTS * I_DIM * 2;
    if (ws_size < need) return;

    hipMemsetAsync(cnt, 0, 32, stream);
    hipMemsetAsync(out, 0, (size_t)T_TOK * H_DIM * sizeof(float), stream);

    router_k<<<T_TOK / 4, 256, 0, stream>>>(x, rw, cnt, tok, wts, xbf);
    prefix_k<<<1, 64, 0, stream>>>(cnt, offs_pad, tile_e, tile_row0, ntiles);
    gateup_k<<<NT_MAX * (I_DIM / 128), 512, 0, stream>>>(
        xbf, wg, wu, cnt, offs_pad, tile_e, tile_row0, ntiles, tok, act);
    down_k<<<NT_MAX * (H_DIM / 128) * 2, 512, 0, stream>>>(
        act, wd, cnt, offs_pad, tile_e, tile_row0, ntiles, tok, wts, out);
}